// Round 9
// baseline (516.844 us; speedup 1.0000x reference)
//
#include <hip/hip_runtime.h>

typedef __bf16 bf16;
typedef __bf16 bf16x8 __attribute__((ext_vector_type(8)));
typedef float f32x4 __attribute__((ext_vector_type(4)));

#define DM 1024
#define NH 16
#define DKK 64
#define BB 4
#define SS 2048
#define MTOT (BB * SS)
// softmax scale folded into Q: 1/sqrt(dk) * log2(e)  (exp2-direct domain)
#define QSC 0.18033688011112042f

__device__ __forceinline__ f32x4 mfma16(bf16x8 a, bf16x8 b, f32x4 c) {
  return __builtin_amdgcn_mfma_f32_16x16x32_bf16(a, b, c, 0, 0, 0);
}

__device__ __forceinline__ void gload_lds(const bf16* g, void* l) {
  __builtin_amdgcn_global_load_lds((const __attribute__((address_space(1))) void*)g,
                                   (__attribute__((address_space(3))) void*)l, 16, 0, 0);
}

// P-LDS swizzle: row stride 128 B; XOR row bits into byte offset (bank spread)
__device__ __forceinline__ int pswz(int row, int colbyte) {
  return row * 128 + (colbyte ^ ((row & 7) << 4));
}

// ---------------- f32 -> bf16 conversion (vectorized, 8 elems/thread) -------
__global__ void cvt_kernel(const float* __restrict__ in, bf16* __restrict__ out) {
  long i = (long)(blockIdx.x * blockDim.x + threadIdx.x) * 8;
  float4 a = *reinterpret_cast<const float4*>(in + i);
  float4 b = *reinterpret_cast<const float4*>(in + i + 4);
  bf16x8 o;
  o[0] = (bf16)a.x; o[1] = (bf16)a.y; o[2] = (bf16)a.z; o[3] = (bf16)a.w;
  o[4] = (bf16)b.x; o[5] = (bf16)b.y; o[6] = (bf16)b.z; o[7] = (bf16)b.w;
  *reinterpret_cast<bf16x8*>(out + i) = o;
}

// ---------------- W[k][n] f32 -> Wt[n][k] bf16 (tiled transpose) ------------
__global__ void transpose_cvt_kernel(const float* __restrict__ w0, const float* __restrict__ w1,
                                     const float* __restrict__ w2, const float* __restrict__ w3,
                                     bf16* __restrict__ o0, bf16* __restrict__ o1,
                                     bf16* __restrict__ o2, bf16* __restrict__ o3) {
  __shared__ float t[32][33];
  int z = blockIdx.z;
  const float* src = z == 0 ? w0 : z == 1 ? w1 : z == 2 ? w2 : w3;
  bf16* dst = z == 0 ? o0 : z == 1 ? o1 : z == 2 ? o2 : o3;
  int n0 = blockIdx.x * 32, k0 = blockIdx.y * 32;
  int tx = threadIdx.x, ty = threadIdx.y;  // (32, 8)
#pragma unroll
  for (int j = 0; j < 4; ++j)
    t[ty + 8 * j][tx] = src[(long)(k0 + ty + 8 * j) * DM + n0 + tx];
  __syncthreads();
#pragma unroll
  for (int j = 0; j < 4; ++j)
    dst[(long)(n0 + ty + 8 * j) * DM + k0 + tx] = (bf16)t[tx][ty + 8 * j];
}

// ---------------- 128x128x32 bf16 GEMM, m97-style global_load_lds staging ---
// A: [M,1024] bf16.  Bt: [1024,1024] bf16 (W^T).  Linear LDS [128][32] x2 dbuf.
// MODE 0: bf16 [B,H,S,dk]; MODE 1: bf16 [B,H,dk,S]; MODE 2: f32 [M,N].
template <int MODE>
__global__ __launch_bounds__(256, 2) void gemm_kernel(const bf16* __restrict__ A,
                                                      const bf16* __restrict__ Bt,
                                                      const float* __restrict__ bias,
                                                      void* __restrict__ Cout, float oscale) {
  __shared__ bf16 As[2][128 * 32];
  __shared__ bf16 Bs[2][128 * 32];
  int tid = threadIdx.x;
  int m0 = blockIdx.x * 128, n0 = blockIdx.y * 128;
  int lane = tid & 63, wid = tid >> 6;
  int wr = wid >> 1, wc = wid & 1;
  int lo = lane & 15, hi = lane >> 4;

  // staging: wave w owns chunks {2w, 2w+1}; chunk c = rows 16c..16c+15.
  // lane l -> row 16c + (l>>2), col (l&3)*8; LDS dest = chunkbase + l*16 (linear)
  int srow0 = 32 * wid + (lane >> 2);
  int scol = (lane & 3) * 8;
  const bf16* Ap0 = A + (long)(m0 + srow0) * DM + scol;
  const bf16* Ap1 = A + (long)(m0 + srow0 + 16) * DM + scol;
  const bf16* Bp0 = Bt + (long)(n0 + srow0) * DM + scol;
  const bf16* Bp1 = Bt + (long)(n0 + srow0 + 16) * DM + scol;
  int cb0 = (2 * wid) * 1024, cb1 = (2 * wid + 1) * 1024;  // chunk byte offsets

  f32x4 acc[4][4] = {};

  // prologue: stage tile 0 into buf 0
  gload_lds(Ap0, (char*)As[0] + cb0);
  gload_lds(Ap1, (char*)As[0] + cb1);
  gload_lds(Bp0, (char*)Bs[0] + cb0);
  gload_lds(Bp1, (char*)Bs[0] + cb1);
  __syncthreads();

  int buf = 0;
  for (int kt = 0; kt < 32; ++kt) {
    if (kt + 1 < 32) {  // issue next-tile staging into the other buffer
      int off = (kt + 1) * 32;
      gload_lds(Ap0 + off, (char*)As[buf ^ 1] + cb0);
      gload_lds(Ap1 + off, (char*)As[buf ^ 1] + cb1);
      gload_lds(Bp0 + off, (char*)Bs[buf ^ 1] + cb0);
      gload_lds(Bp1 + off, (char*)Bs[buf ^ 1] + cb1);
    }
    bf16x8 af[4], bfr[4];
#pragma unroll
    for (int mi = 0; mi < 4; ++mi)
      af[mi] = *(const bf16x8*)&As[buf][(wr * 64 + mi * 16 + lo) * 32 + hi * 8];
#pragma unroll
    for (int ni = 0; ni < 4; ++ni)
      bfr[ni] = *(const bf16x8*)&Bs[buf][(wc * 64 + ni * 16 + lo) * 32 + hi * 8];
#pragma unroll
    for (int mi = 0; mi < 4; ++mi)
#pragma unroll
      for (int ni = 0; ni < 4; ++ni)
        acc[mi][ni] = mfma16(af[mi], bfr[ni], acc[mi][ni]);
    __syncthreads();  // drains vmcnt: next buffer ready, this buffer reusable
    buf ^= 1;
  }

#pragma unroll
  for (int ni = 0; ni < 4; ++ni) {
    int col = n0 + wc * 64 + ni * 16 + lo;
    float bv = bias[col];
#pragma unroll
    for (int mi = 0; mi < 4; ++mi) {
      int rowb = m0 + wr * 64 + mi * 16 + hi * 4;
#pragma unroll
      for (int r = 0; r < 4; ++r) {
        int row = rowb + r;
        float v = (acc[mi][ni][r] + bv) * oscale;
        if (MODE == 0) {
          int b = row >> 11, s = row & 2047, h = col >> 6, d = col & 63;
          ((bf16*)Cout)[(((long)(b * NH + h) * SS + s) << 6) | d] = (bf16)v;
        } else if (MODE == 1) {
          int b = row >> 11, s = row & 2047, h = col >> 6, d = col & 63;
          ((bf16*)Cout)[(((long)(b * NH + h) * DKK + d) << 11) | s] = (bf16)v;
        } else {
          ((float*)Cout)[(long)row * DM + col] = v;
        }
      }
    }
  }
}

// ---------------- causal flash attention (16x16 MFMA, verified conventions) --
// Q (pre-scaled by QSC), K: [B,H,S,64] bf16.  VT: [B,H,64,S] bf16.
// AO: [B,S,1024] bf16.  Grid 1024 blocks x 256 thr; 4 waves x 32 q-rows each;
// KBLK=64.  D-layout: col=lane&15, row=hi*4+reg (verified round 3/8).
__global__ __launch_bounds__(256, 4) void attn_kernel(const bf16* __restrict__ Q,
                                                      const bf16* __restrict__ K,
                                                      const bf16* __restrict__ VT,
                                                      bf16* __restrict__ AO) {
  __shared__ char Pl[4][4096];  // per-wave P tile: 32 rows x 128 B, swizzled
  int bid = blockIdx.x;
  int qt = 15 - (bid >> 6);  // longest q-tiles first (causal tail pack)
  int bh = bid & 63;
  int tid = threadIdx.x, wid = tid >> 6, lane = tid & 63;
  int lo = lane & 15, hi = lane >> 4;
  int q0w = qt * 128 + wid * 32;
  const bf16* Qh = Q + (long)bh * SS * DKK;
  const bf16* Kh = K + (long)bh * SS * DKK;
  const bf16* Vh = VT + (long)bh * DKK * SS;
  char* pw = Pl[wid];

  // Q A-frags: qf[b2][c] = Q[q0w + b2*16 + lo][c*32 + hi*8 + j]
  bf16x8 qf[2][2];
#pragma unroll
  for (int b2 = 0; b2 < 2; ++b2)
#pragma unroll
    for (int c = 0; c < 2; ++c)
      qf[b2][c] = *(const bf16x8*)&Qh[(q0w + b2 * 16 + lo) * DKK + c * 32 + hi * 8];

  f32x4 o[4][2] = {};              // [df][b2]
  float mrun[2][4], lrun[2][4];    // [b2][r]
#pragma unroll
  for (int b2 = 0; b2 < 2; ++b2)
#pragma unroll
    for (int r = 0; r < 4; ++r) { mrun[b2][r] = -1e30f; lrun[b2][r] = 0.f; }

  int ntiles = (q0w + 95) >> 6;
  for (int t = 0; t < ntiles; ++t) {
    int kb = t * 64;
    // ---- QK^T: s[b2][kf] covers q-rows (b2*16+hi*4+r), k-cols (kf*16+lo)
    f32x4 s[2][4];
#pragma unroll
    for (int kf = 0; kf < 4; ++kf) {
      const bf16* kp = &Kh[(kb + kf * 16 + lo) * DKK + hi * 8];
      bf16x8 k0 = *(const bf16x8*)kp;
      bf16x8 k1 = *(const bf16x8*)(kp + 32);
#pragma unroll
      for (int b2 = 0; b2 < 2; ++b2) {
        f32x4 z = {0.f, 0.f, 0.f, 0.f};
        s[b2][kf] = mfma16(qf[b2][1], k1, mfma16(qf[b2][0], k0, z));
      }
    }

    if (t == ntiles - 1) {  // diagonal tile: causal mask
#pragma unroll
      for (int b2 = 0; b2 < 2; ++b2)
#pragma unroll
        for (int kf = 0; kf < 4; ++kf) {
          int kcol = kb + kf * 16 + lo;
#pragma unroll
          for (int r = 0; r < 4; ++r) {
            int qrow = q0w + b2 * 16 + hi * 4 + r;
            if (kcol > qrow) s[b2][kf][r] = -1e30f;
          }
        }
    }

    // ---- row max over 64 k: local fmax across kf, then 4-level shfl_xor
    float pm[2][4];
#pragma unroll
    for (int b2 = 0; b2 < 2; ++b2)
#pragma unroll
      for (int r = 0; r < 4; ++r)
        pm[b2][r] = fmaxf(fmaxf(s[b2][0][r], s[b2][1][r]),
                          fmaxf(s[b2][2][r], s[b2][3][r]));
#pragma unroll
    for (int m = 1; m < 16; m <<= 1)
#pragma unroll
      for (int b2 = 0; b2 < 2; ++b2)
#pragma unroll
        for (int r = 0; r < 4; ++r)
          pm[b2][r] = fmaxf(pm[b2][r], __shfl_xor(pm[b2][r], m, 64));

    // ---- online update + P (bf16) to swizzled LDS + row sum
    float rs[2][4];
#pragma unroll
    for (int b2 = 0; b2 < 2; ++b2)
#pragma unroll
      for (int r = 0; r < 4; ++r) {
        float mnew = fmaxf(mrun[b2][r], pm[b2][r]);
        float corr = exp2f(mrun[b2][r] - mnew);
        mrun[b2][r] = mnew;
        lrun[b2][r] *= corr;
#pragma unroll
        for (int df = 0; df < 4; ++df) o[df][b2][r] *= corr;
        int row = b2 * 16 + hi * 4 + r;
        float rsv = 0.f;
#pragma unroll
        for (int kf = 0; kf < 4; ++kf) {
          float p = exp2f(s[b2][kf][r] - mnew);
          rsv += p;
          *(bf16*)(pw + pswz(row, (kf * 16 + lo) * 2)) = (bf16)p;
        }
        rs[b2][r] = rsv;
      }
#pragma unroll
    for (int m = 1; m < 16; m <<= 1)
#pragma unroll
      for (int b2 = 0; b2 < 2; ++b2)
#pragma unroll
        for (int r = 0; r < 4; ++r)
          rs[b2][r] += __shfl_xor(rs[b2][r], m, 64);
#pragma unroll
    for (int b2 = 0; b2 < 2; ++b2)
#pragma unroll
      for (int r = 0; r < 4; ++r) lrun[b2][r] += rs[b2][r];

    // ---- PV: TWO 32-k steps (k is the MFMA reduction dim, 32 per mfma16).
#pragma unroll
    for (int kk = 0; kk < 2; ++kk) {
      bf16x8 pf[2];
#pragma unroll
      for (int b2 = 0; b2 < 2; ++b2)
        pf[b2] = *(const bf16x8*)(pw + pswz(b2 * 16 + lo, kk * 64 + hi * 16));
#pragma unroll
      for (int df = 0; df < 4; ++df) {
        bf16x8 vf = *(const bf16x8*)&Vh[(df * 16 + lo) * SS + kb + kk * 32 + hi * 8];
#pragma unroll
        for (int b2 = 0; b2 < 2; ++b2)
          o[df][b2] = mfma16(pf[b2], vf, o[df][b2]);
      }
    }
  }

  int b = bh >> 4, h = bh & 15;
  float linv[2][4];
#pragma unroll
  for (int b2 = 0; b2 < 2; ++b2)
#pragma unroll
    for (int r = 0; r < 4; ++r) linv[b2][r] = 1.0f / lrun[b2][r];
#pragma unroll
  for (int b2 = 0; b2 < 2; ++b2)
#pragma unroll
    for (int df = 0; df < 4; ++df)
#pragma unroll
      for (int r = 0; r < 4; ++r) {
        int q = q0w + b2 * 16 + hi * 4 + r;
        AO[(((long)(b * SS + q)) << 10) + h * DKK + df * 16 + lo] =
            (bf16)(o[df][b2][r] * linv[b2][r]);
      }
}

// ---------------- launcher ----------------------------------------------------
extern "C" void kernel_launch(void* const* d_in, const int* in_sizes, int n_in,
                              void* d_out, int out_size, void* d_ws, size_t ws_size,
                              hipStream_t stream) {
  if (ws_size < (72ULL << 20)) return;

  const float* x  = (const float*)d_in[0];
  const float* Wq = (const float*)d_in[1];
  const float* bq = (const float*)d_in[2];
  const float* Wk = (const float*)d_in[3];
  const float* bk = (const float*)d_in[4];
  const float* Wv = (const float*)d_in[5];
  const float* bv = (const float*)d_in[6];
  const float* Wo = (const float*)d_in[7];
  const float* bo = (const float*)d_in[8];

  char* ws = (char*)d_ws;
  bf16* xb  = (bf16*)(ws);                     // 16 MB (later reused as AO)
  bf16* wtq = (bf16*)(ws + (16L << 20));
  bf16* wtk = (bf16*)(ws + (18L << 20));
  bf16* wtv = (bf16*)(ws + (20L << 20));
  bf16* wto = (bf16*)(ws + (22L << 20));
  bf16* Qb  = (bf16*)(ws + (24L << 20));
  bf16* Kb  = (bf16*)(ws + (40L << 20));
  bf16* VTb = (bf16*)(ws + (56L << 20));
  bf16* AO  = xb;

  cvt_kernel<<<(MTOT * DM) / (256 * 8), 256, 0, stream>>>(x, xb);
  transpose_cvt_kernel<<<dim3(32, 32, 4), dim3(32, 8), 0, stream>>>(
      Wq, Wk, Wv, Wo, wtq, wtk, wtv, wto);

  gemm_kernel<0><<<dim3(64, 8), 256, 0, stream>>>(xb, wtq, bq, (void*)Qb, QSC);
  gemm_kernel<0><<<dim3(64, 8), 256, 0, stream>>>(xb, wtk, bk, (void*)Kb, 1.0f);
  gemm_kernel<1><<<dim3(64, 8), 256, 0, stream>>>(xb, wtv, bv, (void*)VTb, 1.0f);

  attn_kernel<<<dim3(1024), 256, 0, stream>>>(Qb, Kb, VTb, AO);

  gemm_kernel<2><<<dim3(64, 8), 256, 0, stream>>>(AO, wto, bo, d_out, 1.0f);
}

// Round 10
// 352.533 us; speedup vs baseline: 1.4661x; 1.4661x over previous
//
#include <hip/hip_runtime.h>

typedef __bf16 bf16;
typedef __bf16 bf16x8 __attribute__((ext_vector_type(8)));
typedef float f32x4 __attribute__((ext_vector_type(4)));

#define DM 1024
#define NH 16
#define DKK 64
#define BB 4
#define SS 2048
#define MTOT (BB * SS)
// softmax scale folded into Q: 1/sqrt(dk) * log2(e)  (exp2-direct domain)
#define QSC 0.18033688011112042f

__device__ __forceinline__ f32x4 mfma16(bf16x8 a, bf16x8 b, f32x4 c) {
  return __builtin_amdgcn_mfma_f32_16x16x32_bf16(a, b, c, 0, 0, 0);
}

__device__ __forceinline__ void gload_lds(const bf16* g, void* l) {
  __builtin_amdgcn_global_load_lds((const __attribute__((address_space(1))) void*)g,
                                   (__attribute__((address_space(3))) void*)l, 16, 0, 0);
}

// P-LDS swizzle: row stride 128 B; XOR row bits into byte offset (bank spread).
// Flips byte bits 4..6 only -> preserves 8B/16B alignment. Verified 0-conflict (r8).
__device__ __forceinline__ int pswz(int row, int colbyte) {
  return row * 128 + (colbyte ^ ((row & 7) << 4));
}

// ---------------- f32 -> bf16 conversion (vectorized, 8 elems/thread) -------
__global__ void cvt_kernel(const float* __restrict__ in, bf16* __restrict__ out) {
  long i = (long)(blockIdx.x * blockDim.x + threadIdx.x) * 8;
  float4 a = *reinterpret_cast<const float4*>(in + i);
  float4 b = *reinterpret_cast<const float4*>(in + i + 4);
  bf16x8 o;
  o[0] = (bf16)a.x; o[1] = (bf16)a.y; o[2] = (bf16)a.z; o[3] = (bf16)a.w;
  o[4] = (bf16)b.x; o[5] = (bf16)b.y; o[6] = (bf16)b.z; o[7] = (bf16)b.w;
  *reinterpret_cast<bf16x8*>(out + i) = o;
}

// ---------------- W[k][n] f32 -> Wt[n][k] bf16 (tiled transpose) ------------
__global__ void transpose_cvt_kernel(const float* __restrict__ w0, const float* __restrict__ w1,
                                     const float* __restrict__ w2, const float* __restrict__ w3,
                                     bf16* __restrict__ o0, bf16* __restrict__ o1,
                                     bf16* __restrict__ o2, bf16* __restrict__ o3) {
  __shared__ float t[32][33];
  int z = blockIdx.z;
  const float* src = z == 0 ? w0 : z == 1 ? w1 : z == 2 ? w2 : w3;
  bf16* dst = z == 0 ? o0 : z == 1 ? o1 : z == 2 ? o2 : o3;
  int n0 = blockIdx.x * 32, k0 = blockIdx.y * 32;
  int tx = threadIdx.x, ty = threadIdx.y;  // (32, 8)
#pragma unroll
  for (int j = 0; j < 4; ++j)
    t[ty + 8 * j][tx] = src[(long)(k0 + ty + 8 * j) * DM + n0 + tx];
  __syncthreads();
#pragma unroll
  for (int j = 0; j < 4; ++j)
    dst[(long)(n0 + ty + 8 * j) * DM + k0 + tx] = (bf16)t[tx][ty + 8 * j];
}

// ---------------- 128x128x32 bf16 GEMM, m97-style global_load_lds staging ---
template <int MODE>
__global__ __launch_bounds__(256, 2) void gemm_kernel(const bf16* __restrict__ A,
                                                      const bf16* __restrict__ Bt,
                                                      const float* __restrict__ bias,
                                                      void* __restrict__ Cout, float oscale) {
  __shared__ bf16 As[2][128 * 32];
  __shared__ bf16 Bs[2][128 * 32];
  int tid = threadIdx.x;
  int m0 = blockIdx.x * 128, n0 = blockIdx.y * 128;
  int lane = tid & 63, wid = tid >> 6;
  int wr = wid >> 1, wc = wid & 1;
  int lo = lane & 15, hi = lane >> 4;

  int srow0 = 32 * wid + (lane >> 2);
  int scol = (lane & 3) * 8;
  const bf16* Ap0 = A + (long)(m0 + srow0) * DM + scol;
  const bf16* Ap1 = A + (long)(m0 + srow0 + 16) * DM + scol;
  const bf16* Bp0 = Bt + (long)(n0 + srow0) * DM + scol;
  const bf16* Bp1 = Bt + (long)(n0 + srow0 + 16) * DM + scol;
  int cb0 = (2 * wid) * 1024, cb1 = (2 * wid + 1) * 1024;

  f32x4 acc[4][4] = {};

  gload_lds(Ap0, (char*)As[0] + cb0);
  gload_lds(Ap1, (char*)As[0] + cb1);
  gload_lds(Bp0, (char*)Bs[0] + cb0);
  gload_lds(Bp1, (char*)Bs[0] + cb1);
  __syncthreads();

  int buf = 0;
  for (int kt = 0; kt < 32; ++kt) {
    if (kt + 1 < 32) {
      int off = (kt + 1) * 32;
      gload_lds(Ap0 + off, (char*)As[buf ^ 1] + cb0);
      gload_lds(Ap1 + off, (char*)As[buf ^ 1] + cb1);
      gload_lds(Bp0 + off, (char*)Bs[buf ^ 1] + cb0);
      gload_lds(Bp1 + off, (char*)Bs[buf ^ 1] + cb1);
    }
    bf16x8 af[4], bfr[4];
#pragma unroll
    for (int mi = 0; mi < 4; ++mi)
      af[mi] = *(const bf16x8*)&As[buf][(wr * 64 + mi * 16 + lo) * 32 + hi * 8];
#pragma unroll
    for (int ni = 0; ni < 4; ++ni)
      bfr[ni] = *(const bf16x8*)&Bs[buf][(wc * 64 + ni * 16 + lo) * 32 + hi * 8];
#pragma unroll
    for (int mi = 0; mi < 4; ++mi)
#pragma unroll
      for (int ni = 0; ni < 4; ++ni)
        acc[mi][ni] = mfma16(af[mi], bfr[ni], acc[mi][ni]);
    __syncthreads();
    buf ^= 1;
  }

#pragma unroll
  for (int ni = 0; ni < 4; ++ni) {
    int col = n0 + wc * 64 + ni * 16 + lo;
    float bv = bias[col];
#pragma unroll
    for (int mi = 0; mi < 4; ++mi) {
      int rowb = m0 + wr * 64 + mi * 16 + hi * 4;
#pragma unroll
      for (int r = 0; r < 4; ++r) {
        int row = rowb + r;
        float v = (acc[mi][ni][r] + bv) * oscale;
        if (MODE == 0) {
          int b = row >> 11, s = row & 2047, h = col >> 6, d = col & 63;
          ((bf16*)Cout)[(((long)(b * NH + h) * SS + s) << 6) | d] = (bf16)v;
        } else if (MODE == 1) {
          int b = row >> 11, s = row & 2047, h = col >> 6, d = col & 63;
          ((bf16*)Cout)[(((long)(b * NH + h) * DKK + d) << 11) | s] = (bf16)v;
        } else {
          ((float*)Cout)[(long)row * DM + col] = v;
        }
      }
    }
  }
}

// ---------------- causal flash attention, SWAPPED QK^T (16x16, verified) -----
// Q (pre-scaled), K: [B,H,S,64].  VT: [B,H,64,S].  AO: [B,S,1024] bf16.
// 4 waves x 32 q-rows (2 groups of 16).  S^T = mfma16(K-frag, Q-frag):
// D row = k = hi*4+r (+16f), col = q = lo  ->  softmax state is LANE-LOCAL
// (q = lo): row-reduce = 15 local fmax + 2 shfl_xor.  Same fragment
// conventions as the verified GEMM/QK/PV; only A/B roles swap.
__global__ __launch_bounds__(256, 2) void attn_kernel(const bf16* __restrict__ Q,
                                                      const bf16* __restrict__ K,
                                                      const bf16* __restrict__ VT,
                                                      bf16* __restrict__ AO) {
  __shared__ char Pl[4][4096];  // per-wave P: 32 rows x 128 B, swizzled
  int bid = blockIdx.x;
  int qt = 15 - (bid >> 6);
  int bh = bid & 63;
  int tid = threadIdx.x, wid = tid >> 6, lane = tid & 63;
  int lo = lane & 15, hi = lane >> 4;
  int q0w = qt * 128 + wid * 32;
  const bf16* Qh = Q + (long)bh * SS * DKK;
  const bf16* Kh = K + (long)bh * SS * DKK;
  const bf16* Vh = VT + (long)bh * DKK * SS;
  char* pw = Pl[wid];

  // Q B-frags: qf[g][c] = Q[q0w + g*16 + lo][c*32 + hi*8 + j]
  bf16x8 qf[2][2];
#pragma unroll
  for (int g = 0; g < 2; ++g)
#pragma unroll
    for (int c = 0; c < 2; ++c)
      qf[g][c] = *(const bf16x8*)&Qh[(q0w + g * 16 + lo) * DKK + c * 32 + hi * 8];

  f32x4 o[4][2] = {};                     // [df][g]; D rows q=hi*4+r, col d=lo
  float m_run[2] = {-1e30f, -1e30f};      // per-lane: q = q0w + g*16 + lo
  float l_run[2] = {0.f, 0.f};

  int ntiles = (q0w + 95) >> 6;
  for (int t = 0; t < ntiles; ++t) {
    int kb = t * 64;
    // ---- S^T[k][q]: s[g][f][r] = S[k=kb+f*16+hi*4+r][q=q0w+g*16+lo]
    f32x4 s[2][4];
#pragma unroll
    for (int f = 0; f < 4; ++f) {
      const bf16* kp = &Kh[(kb + f * 16 + lo) * DKK + hi * 8];
      bf16x8 k0 = *(const bf16x8*)kp;
      bf16x8 k1 = *(const bf16x8*)(kp + 32);
#pragma unroll
      for (int g = 0; g < 2; ++g) {
        f32x4 z = {0.f, 0.f, 0.f, 0.f};
        s[g][f] = mfma16(k1, qf[g][1], mfma16(k0, qf[g][0], z));
      }
    }

    if (t == ntiles - 1) {  // diagonal tile: causal mask (k > q)
#pragma unroll
      for (int g = 0; g < 2; ++g) {
        int qg = q0w + g * 16 + lo;
#pragma unroll
        for (int f = 0; f < 4; ++f) {
          int kbase = kb + f * 16 + hi * 4;
#pragma unroll
          for (int r = 0; r < 4; ++r)
            if (kbase + r > qg) s[g][f][r] = -1e30f;
        }
      }
    }

#pragma unroll
    for (int g = 0; g < 2; ++g) {
      // row max: 15 local fmax + 2 shfl_xor (merge 4 hi-quadrants)
      float pm = fmaxf(fmaxf(fmaxf(s[g][0][0], s[g][0][1]), fmaxf(s[g][0][2], s[g][0][3])),
                       fmaxf(fmaxf(s[g][1][0], s[g][1][1]), fmaxf(s[g][1][2], s[g][1][3])));
      pm = fmaxf(pm,
                 fmaxf(fmaxf(fmaxf(s[g][2][0], s[g][2][1]), fmaxf(s[g][2][2], s[g][2][3])),
                       fmaxf(fmaxf(s[g][3][0], s[g][3][1]), fmaxf(s[g][3][2], s[g][3][3]))));
      pm = fmaxf(pm, __shfl_xor(pm, 16, 64));
      pm = fmaxf(pm, __shfl_xor(pm, 32, 64));

      float mnew = fmaxf(m_run[g], pm);
      float corr = exp2f(m_run[g] - mnew);
      m_run[g] = mnew;

      // P = exp2(s - m), in place; local sum
      float rs = 0.f;
#pragma unroll
      for (int f = 0; f < 4; ++f)
#pragma unroll
        for (int r = 0; r < 4; ++r) {
          float p = exp2f(s[g][f][r] - mnew);
          s[g][f][r] = p;
          rs += p;
        }
      rs += __shfl_xor(rs, 16, 64);
      rs += __shfl_xor(rs, 32, 64);
      l_run[g] = l_run[g] * corr + rs;

      // rescale O rows (q = q0w+g*16+hi*4+r): corr lives at lane hi*4+r
      float c0 = __shfl(corr, hi * 4 + 0, 64);
      float c1 = __shfl(corr, hi * 4 + 1, 64);
      float c2 = __shfl(corr, hi * 4 + 2, 64);
      float c3 = __shfl(corr, hi * 4 + 3, 64);
#pragma unroll
      for (int df = 0; df < 4; ++df) {
        o[df][g][0] *= c0; o[df][g][1] *= c1;
        o[df][g][2] *= c2; o[df][g][3] *= c3;
      }

      // write P to LDS: row = g*16+lo, k = f*16+hi*4+r -> one b64 per f
#pragma unroll
      for (int f = 0; f < 4; ++f) {
        union { bf16 h[4]; unsigned long long u; } pk;
        pk.h[0] = (bf16)s[g][f][0]; pk.h[1] = (bf16)s[g][f][1];
        pk.h[2] = (bf16)s[g][f][2]; pk.h[3] = (bf16)s[g][f][3];
        *(unsigned long long*)(pw + pswz(g * 16 + lo, f * 32 + hi * 8)) = pk.u;
      }
    }

    // ---- PV: A = P (rows q=lo, k=kk*32+hi*8+j), B = VT rows
#pragma unroll
    for (int kk = 0; kk < 2; ++kk) {
      bf16x8 pf[2];
#pragma unroll
      for (int g = 0; g < 2; ++g)
        pf[g] = *(const bf16x8*)(pw + pswz(g * 16 + lo, kk * 64 + hi * 16));
#pragma unroll
      for (int df = 0; df < 4; ++df) {
        bf16x8 vf = *(const bf16x8*)&Vh[(df * 16 + lo) * SS + kb + kk * 32 + hi * 8];
#pragma unroll
        for (int g = 0; g < 2; ++g)
          o[df][g] = mfma16(pf[g], vf, o[df][g]);
      }
    }
  }

  int b = bh >> 4, h = bh & 15;
  float li[2][4];
#pragma unroll
  for (int g = 0; g < 2; ++g) {
    float linv = 1.0f / l_run[g];
#pragma unroll
    for (int r = 0; r < 4; ++r) li[g][r] = __shfl(linv, hi * 4 + r, 64);
  }
#pragma unroll
  for (int g = 0; g < 2; ++g)
#pragma unroll
    for (int df = 0; df < 4; ++df)
#pragma unroll
      for (int r = 0; r < 4; ++r) {
        int q = q0w + g * 16 + hi * 4 + r;
        AO[(((long)(b * SS + q)) << 10) + h * DKK + df * 16 + lo] =
            (bf16)(o[df][g][r] * li[g][r]);
      }
}

// ---------------- launcher ----------------------------------------------------
extern "C" void kernel_launch(void* const* d_in, const int* in_sizes, int n_in,
                              void* d_out, int out_size, void* d_ws, size_t ws_size,
                              hipStream_t stream) {
  if (ws_size < (72ULL << 20)) return;

  const float* x  = (const float*)d_in[0];
  const float* Wq = (const float*)d_in[1];
  const float* bq = (const float*)d_in[2];
  const float* Wk = (const float*)d_in[3];
  const float* bk = (const float*)d_in[4];
  const float* Wv = (const float*)d_in[5];
  const float* bv = (const float*)d_in[6];
  const float* Wo = (const float*)d_in[7];
  const float* bo = (const float*)d_in[8];

  char* ws = (char*)d_ws;
  bf16* xb  = (bf16*)(ws);                     // 16 MB (later reused as AO)
  bf16* wtq = (bf16*)(ws + (16L << 20));
  bf16* wtk = (bf16*)(ws + (18L << 20));
  bf16* wtv = (bf16*)(ws + (20L << 20));
  bf16* wto = (bf16*)(ws + (22L << 20));
  bf16* Qb  = (bf16*)(ws + (24L << 20));
  bf16* Kb  = (bf16*)(ws + (40L << 20));
  bf16* VTb = (bf16*)(ws + (56L << 20));
  bf16* AO  = xb;

  cvt_kernel<<<(MTOT * DM) / (256 * 8), 256, 0, stream>>>(x, xb);
  transpose_cvt_kernel<<<dim3(32, 32, 4), dim3(32, 8), 0, stream>>>(
      Wq, Wk, Wv, Wo, wtq, wtk, wtv, wto);

  gemm_kernel<0><<<dim3(64, 8), 256, 0, stream>>>(xb, wtq, bq, (void*)Qb, QSC);
  gemm_kernel<0><<<dim3(64, 8), 256, 0, stream>>>(xb, wtk, bk, (void*)Kb, 1.0f);
  gemm_kernel<1><<<dim3(64, 8), 256, 0, stream>>>(xb, wtv, bv, (void*)VTb, 1.0f);

  attn_kernel<<<dim3(1024), 256, 0, stream>>>(Qb, Kb, VTb, AO);

  gemm_kernel<2><<<dim3(64, 8), 256, 0, stream>>>(AO, wto, bo, d_out, 1.0f);
}